// Round 10
// baseline (523.231 us; speedup 1.0000x reference)
//
#include <hip/hip_runtime.h>
#include <math.h>

#define B 256
#define D 256
#define M 100000
#define C 5000
#define TEMPF 0.05f
#define EPSF 1e-6f

// ws layout (float offsets)
#define OFF_G 0                      // C*D = 1,280,000 floats
#define OFF_NUMS (C * D)             // 5000 floats (padded to 5120)
#define OFF_X (OFF_NUMS + 5120)      // B*D floats
#define OFF_SIM (OFF_X + B * D)      // B*C floats
#define OFF_LOSS (OFF_SIM + B * C)   // B floats
// total ~2,630,912 floats = 10.5 MB of ws

// ---------------- aggregation: G[c][d] = sum of features rows with label c ----
__global__ void k_aggregate(const float* __restrict__ feats,
                            const int* __restrict__ labels,
                            float* __restrict__ ws) {
    float* Gm = ws + OFF_G;
    float* nums = ws + OFF_NUMS;
    const int total4 = M * (D / 4);  // 6,400,000 float4s
    const int stride = gridDim.x * blockDim.x;
    for (int i = blockIdx.x * blockDim.x + threadIdx.x; i < total4; i += stride) {
        int m = i >> 6;   // 64 float4 per row
        int d4 = i & 63;
        int lab = labels[m];
        const float4 v = reinterpret_cast<const float4*>(feats)[i];
        float* g = Gm + (size_t)lab * D + d4 * 4;
        atomicAdd(g + 0, v.x);
        atomicAdd(g + 1, v.y);
        atomicAdd(g + 2, v.z);
        atomicAdd(g + 3, v.w);
        if (d4 == 0) atomicAdd(nums + lab, 1.0f);
    }
}

// ---------------- L2-normalize the batch inputs ------------------------------
__global__ void k_normalize(const float* __restrict__ in, float* __restrict__ ws) {
    int b = blockIdx.x;
    int t = threadIdx.x;  // 256 threads, one per feature dim
    float v = in[b * D + t];
    float sq = v * v;
    #pragma unroll
    for (int o = 32; o; o >>= 1) sq += __shfl_down(sq, o, 64);
    __shared__ float s[4];
    if ((t & 63) == 0) s[t >> 6] = sq;
    __syncthreads();
    float norm = sqrtf(s[0] + s[1] + s[2] + s[3]);
    float inv = 1.0f / fmaxf(norm, 1e-12f);
    ws[OFF_X + b * D + t] = v * inv;
}

// ---------------- sim = (X @ G^T) / (TEMP * max(nums,1)) ---------------------
#define BT 64
#define CT 64
#define KT 64
__global__ __launch_bounds__(256) void k_gemm(float* __restrict__ ws) {
    const float* X = ws + OFF_X;
    const float* Gm = ws + OFF_G;
    const float* nums = ws + OFF_NUMS;
    float* SIM = ws + OFF_SIM;

    __shared__ float xs[KT][BT + 1];
    __shared__ float gs[KT][CT + 1];

    const int c0 = blockIdx.x * CT;
    const int b0 = blockIdx.y * BT;
    const int t = threadIdx.x;
    const int tx = t & 15, ty = t >> 4;

    float acc[4][4] = {};

    for (int k0 = 0; k0 < D; k0 += KT) {
        for (int i = t; i < BT * KT; i += 256) {
            int r = i >> 6;
            int k = i & 63;
            xs[k][r] = X[(b0 + r) * D + k0 + k];
        }
        for (int i = t; i < CT * KT; i += 256) {
            int r = i >> 6;
            int k = i & 63;
            int c = c0 + r;
            gs[k][r] = (c < C) ? Gm[(size_t)c * D + k0 + k] : 0.0f;
        }
        __syncthreads();
        #pragma unroll 8
        for (int k = 0; k < KT; ++k) {
            float a[4], bb[4];
            #pragma unroll
            for (int i = 0; i < 4; ++i) a[i] = xs[k][ty * 4 + i];
            #pragma unroll
            for (int j = 0; j < 4; ++j) bb[j] = gs[k][tx * 4 + j];
            #pragma unroll
            for (int i = 0; i < 4; ++i)
                #pragma unroll
                for (int j = 0; j < 4; ++j)
                    acc[i][j] += a[i] * bb[j];
        }
        __syncthreads();
    }

    #pragma unroll
    for (int j = 0; j < 4; ++j) {
        int c = c0 + tx * 4 + j;
        if (c < C) {
            float n = nums[c];
            float scale = 1.0f / (TEMPF * (n > 0.0f ? n : 1.0f));
            #pragma unroll
            for (int i = 0; i < 4; ++i) {
                SIM[(size_t)(b0 + ty * 4 + i) * C + c] = acc[i][j] * scale;
            }
        }
    }
}

// ---------------- per-row masked exp-sum + target NLL ------------------------
__global__ void k_loss(const int* __restrict__ indexes,
                       const int* __restrict__ labels,
                       float* __restrict__ ws) {
    int b = blockIdx.x;
    int t = threadIdx.x;
    const float* simrow = ws + OFF_SIM + (size_t)b * C;
    const float* nums = ws + OFF_NUMS;
    float s = 0.0f;
    for (int c = t; c < C; c += 256) {
        if (nums[c] > 0.0f) s += expf(simrow[c]);
    }
    #pragma unroll
    for (int o = 32; o; o >>= 1) s += __shfl_down(s, o, 64);
    __shared__ float sh[4];
    if ((t & 63) == 0) sh[t >> 6] = s;
    __syncthreads();
    if (t == 0) {
        float S = sh[0] + sh[1] + sh[2] + sh[3];
        int tgt = labels[indexes[b]];
        float p = expf(simrow[tgt]) / (S + EPSF) + EPSF;
        ws[OFF_LOSS + b] = -logf(p);
    }
}

__global__ void k_reduce(const float* __restrict__ ws, float* __restrict__ out) {
    int t = threadIdx.x;  // 256 threads, B=256 values
    float v = ws[OFF_LOSS + t];
    #pragma unroll
    for (int o = 32; o; o >>= 1) v += __shfl_down(v, o, 64);
    __shared__ float sh[4];
    if ((t & 63) == 0) sh[t >> 6] = v;
    __syncthreads();
    if (t == 0) out[0] = (sh[0] + sh[1] + sh[2] + sh[3]) * (1.0f / B);
}

extern "C" void kernel_launch(void* const* d_in, const int* in_sizes, int n_in,
                              void* d_out, int out_size, void* d_ws, size_t ws_size,
                              hipStream_t stream) {
    const float* inputs = (const float*)d_in[0];
    const int* indexes = (const int*)d_in[1];
    const float* feats = (const float*)d_in[2];
    const int* labels = (const int*)d_in[3];
    float* ws = (float*)d_ws;
    float* out = (float*)d_out;

    // zero G + nums (ws is poisoned 0xAA before every timed call)
    hipMemsetAsync(d_ws, 0, (size_t)(OFF_NUMS + 5120) * sizeof(float), stream);

    k_aggregate<<<2048, 256, 0, stream>>>(feats, labels, ws);
    k_normalize<<<B, 256, 0, stream>>>(inputs, ws);
    k_gemm<<<dim3((C + CT - 1) / CT, B / BT), 256, 0, stream>>>(ws);
    k_loss<<<B, 256, 0, stream>>>(indexes, labels, ws);
    k_reduce<<<1, 256, 0, stream>>>(ws, out);
}

// Round 13
// 252.497 us; speedup vs baseline: 2.0722x; 2.0722x over previous
//
#include <hip/hip_runtime.h>
#include <math.h>

#define B 256
#define D 256
#define M 100000
#define C 5000
#define TEMPF 0.05f
#define EPSF 1e-6f

// ---- float ws layout (float offsets) ----
#define OFF_G 0                      // C*D
#define OFF_NUMS (C * D)             // 5120
#define OFF_X (OFF_NUMS + 5120)      // B*D
#define OFF_SIM (OFF_X + B * D)      // B*C
#define OFF_LOSS (OFF_SIM + B * C)   // 256
#define OFF_I (OFF_LOSS + 256)       // int region starts here (float-offset)
// ---- int region (int offsets from OFF_I) ----
#define I_COUNTS 0                   // 5120
#define I_STARTS 5120                // 5121
#define I_CURSOR (5120 + 5121)       // 5120
#define I_PERM   (5120 + 5121 + 5120) // M
#define I_TOTAL  (I_PERM + M)
#define WS_NEED ((size_t)OFF_I * 4 + (size_t)I_TOTAL * 4)  // ~11.0 MB

// ================= sort-based aggregation (no hot atomics) ==================
__global__ void k_hist(const int* __restrict__ labels, float* __restrict__ ws) {
    int m = blockIdx.x * blockDim.x + threadIdx.x;
    if (m < M) {
        int* counts = (int*)(ws + OFF_I) + I_COUNTS;
        atomicAdd(&counts[labels[m]], 1);
    }
}

__global__ void k_scan(float* __restrict__ ws) {
    int* I0 = (int*)(ws + OFF_I);
    int* counts = I0 + I_COUNTS;
    int* starts = I0 + I_STARTS;
    int* cursor = I0 + I_CURSOR;
    float* nums = ws + OFF_NUMS;
    const int t = threadIdx.x;
    const int CH = 20;  // 256*20 = 5120 >= C
    int lo = t * CH;
    int hi = lo + CH; if (hi > C) hi = C;
    int lsum = 0;
    for (int i = lo; i < hi; ++i) lsum += counts[i];
    __shared__ int sh[256];
    sh[t] = lsum;
    __syncthreads();
    for (int off = 1; off < 256; off <<= 1) {
        int v = sh[t];
        int o = (t >= off) ? sh[t - off] : 0;
        __syncthreads();
        sh[t] = v + o;
        __syncthreads();
    }
    int excl = sh[t] - lsum;  // exclusive prefix of this thread's chunk
    int running = excl;
    for (int i = lo; i < hi; ++i) {
        int c = counts[i];
        starts[i] = running;
        cursor[i] = running;
        nums[i] = (float)c;
        running += c;
    }
    if (t == 0) starts[C] = M;
}

__global__ void k_scatter(const int* __restrict__ labels, float* __restrict__ ws) {
    int m = blockIdx.x * blockDim.x + threadIdx.x;
    if (m < M) {
        int* I0 = (int*)(ws + OFF_I);
        int* cursor = I0 + I_CURSOR;
        int* perm = I0 + I_PERM;
        int pos = atomicAdd(&cursor[labels[m]], 1);
        perm[pos] = m;
    }
}

// one block per class; thread t owns column t; rows read fully coalesced
__global__ __launch_bounds__(256) void k_gsum(const float* __restrict__ feats,
                                              float* __restrict__ ws) {
    const int c = blockIdx.x;
    const int t = threadIdx.x;
    const int* I0 = (const int*)(ws + OFF_I);
    const int* starts = I0 + I_STARTS;
    const int* perm = I0 + I_PERM;
    float* Gm = ws + OFF_G;
    int s = starts[c], e = starts[c + 1];
    float acc = 0.0f;
    int r = s;
    for (; r + 1 < e; r += 2) {
        int m0 = perm[r], m1 = perm[r + 1];
        float v0 = feats[(size_t)m0 * D + t];
        float v1 = feats[(size_t)m1 * D + t];
        acc += v0 + v1;
    }
    if (r < e) acc += feats[(size_t)perm[r] * D + t];
    Gm[(size_t)c * D + t] = acc;
}

// ============ fallback: atomic aggregation (proven correct r10) =============
__global__ void k_aggregate(const float* __restrict__ feats,
                            const int* __restrict__ labels,
                            float* __restrict__ ws) {
    float* Gm = ws + OFF_G;
    float* nums = ws + OFF_NUMS;
    const int total4 = M * (D / 4);
    const int stride = gridDim.x * blockDim.x;
    for (int i = blockIdx.x * blockDim.x + threadIdx.x; i < total4; i += stride) {
        int m = i >> 6;
        int d4 = i & 63;
        int lab = labels[m];
        const float4 v = reinterpret_cast<const float4*>(feats)[i];
        float* g = Gm + (size_t)lab * D + d4 * 4;
        atomicAdd(g + 0, v.x);
        atomicAdd(g + 1, v.y);
        atomicAdd(g + 2, v.z);
        atomicAdd(g + 3, v.w);
        if (d4 == 0) atomicAdd(nums + lab, 1.0f);
    }
}

// ---------------- L2-normalize the batch inputs ------------------------------
__global__ void k_normalize(const float* __restrict__ in, float* __restrict__ ws) {
    int b = blockIdx.x;
    int t = threadIdx.x;
    float v = in[b * D + t];
    float sq = v * v;
    #pragma unroll
    for (int o = 32; o; o >>= 1) sq += __shfl_down(sq, o, 64);
    __shared__ float s[4];
    if ((t & 63) == 0) s[t >> 6] = sq;
    __syncthreads();
    float norm = sqrtf(s[0] + s[1] + s[2] + s[3]);
    float inv = 1.0f / fmaxf(norm, 1e-12f);
    ws[OFF_X + b * D + t] = v * inv;
}

// ---------------- sim = (X @ G^T) / (TEMP * max(nums,1)) ---------------------
#define BT 64
#define CT 64
#define KT 64
__global__ __launch_bounds__(256) void k_gemm(float* __restrict__ ws) {
    const float* X = ws + OFF_X;
    const float* Gm = ws + OFF_G;
    const float* nums = ws + OFF_NUMS;
    float* SIM = ws + OFF_SIM;

    __shared__ float xs[KT][BT + 1];
    __shared__ float gs[KT][CT + 1];

    const int c0 = blockIdx.x * CT;
    const int b0 = blockIdx.y * BT;
    const int t = threadIdx.x;
    const int tx = t & 15, ty = t >> 4;

    float acc[4][4] = {};

    for (int k0 = 0; k0 < D; k0 += KT) {
        for (int i = t; i < BT * KT; i += 256) {
            int r = i >> 6;
            int k = i & 63;
            xs[k][r] = X[(b0 + r) * D + k0 + k];
        }
        for (int i = t; i < CT * KT; i += 256) {
            int r = i >> 6;
            int k = i & 63;
            int c = c0 + r;
            gs[k][r] = (c < C) ? Gm[(size_t)c * D + k0 + k] : 0.0f;
        }
        __syncthreads();
        #pragma unroll 8
        for (int k = 0; k < KT; ++k) {
            float a[4], bb[4];
            #pragma unroll
            for (int i = 0; i < 4; ++i) a[i] = xs[k][ty * 4 + i];
            #pragma unroll
            for (int j = 0; j < 4; ++j) bb[j] = gs[k][tx * 4 + j];
            #pragma unroll
            for (int i = 0; i < 4; ++i)
                #pragma unroll
                for (int j = 0; j < 4; ++j)
                    acc[i][j] += a[i] * bb[j];
        }
        __syncthreads();
    }

    #pragma unroll
    for (int j = 0; j < 4; ++j) {
        int c = c0 + tx * 4 + j;
        if (c < C) {
            float n = nums[c];
            float scale = 1.0f / (TEMPF * (n > 0.0f ? n : 1.0f));
            #pragma unroll
            for (int i = 0; i < 4; ++i) {
                SIM[(size_t)(b0 + ty * 4 + i) * C + c] = acc[i][j] * scale;
            }
        }
    }
}

// ---------------- per-row masked exp-sum + target NLL ------------------------
__global__ void k_loss(const int* __restrict__ indexes,
                       const int* __restrict__ labels,
                       float* __restrict__ ws) {
    int b = blockIdx.x;
    int t = threadIdx.x;
    const float* simrow = ws + OFF_SIM + (size_t)b * C;
    const float* nums = ws + OFF_NUMS;
    float s = 0.0f;
    for (int c = t; c < C; c += 256) {
        if (nums[c] > 0.0f) s += expf(simrow[c]);
    }
    #pragma unroll
    for (int o = 32; o; o >>= 1) s += __shfl_down(s, o, 64);
    __shared__ float sh[4];
    if ((t & 63) == 0) sh[t >> 6] = s;
    __syncthreads();
    if (t == 0) {
        float S = sh[0] + sh[1] + sh[2] + sh[3];
        int tgt = labels[indexes[b]];
        float p = expf(simrow[tgt]) / (S + EPSF) + EPSF;
        ws[OFF_LOSS + b] = -logf(p);
    }
}

__global__ void k_reduce(const float* __restrict__ ws, float* __restrict__ out) {
    int t = threadIdx.x;
    float v = ws[OFF_LOSS + t];
    #pragma unroll
    for (int o = 32; o; o >>= 1) v += __shfl_down(v, o, 64);
    __shared__ float sh[4];
    if ((t & 63) == 0) sh[t >> 6] = v;
    __syncthreads();
    if (t == 0) out[0] = (sh[0] + sh[1] + sh[2] + sh[3]) * (1.0f / B);
}

extern "C" void kernel_launch(void* const* d_in, const int* in_sizes, int n_in,
                              void* d_out, int out_size, void* d_ws, size_t ws_size,
                              hipStream_t stream) {
    const float* inputs = (const float*)d_in[0];
    const int* indexes = (const int*)d_in[1];
    const float* feats = (const float*)d_in[2];
    const int* labels = (const int*)d_in[3];
    float* ws = (float*)d_ws;
    float* out = (float*)d_out;

    if (ws_size >= WS_NEED) {
        // sort-based aggregation: only counts need zeroing (20 KB)
        hipMemsetAsync((char*)d_ws + (size_t)OFF_I * 4, 0, 5120 * sizeof(int), stream);
        k_hist<<<(M + 255) / 256, 256, 0, stream>>>(labels, ws);
        k_scan<<<1, 256, 0, stream>>>(ws);
        k_scatter<<<(M + 255) / 256, 256, 0, stream>>>(labels, ws);
        k_gsum<<<C, 256, 0, stream>>>(feats, ws);
    } else {
        // fallback: atomic path (r10-proven)
        hipMemsetAsync(d_ws, 0, (size_t)(OFF_NUMS + 5120) * sizeof(float), stream);
        k_aggregate<<<2048, 256, 0, stream>>>(feats, labels, ws);
    }
    k_normalize<<<B, 256, 0, stream>>>(inputs, ws);
    k_gemm<<<dim3((C + CT - 1) / CT, B / BT), 256, 0, stream>>>(ws);
    k_loss<<<B, 256, 0, stream>>>(indexes, labels, ws);
    k_reduce<<<1, 256, 0, stream>>>(ws, out);
}